// Round 7
// baseline (136.700 us; speedup 1.0000x reference)
//
#include <hip/hip_runtime.h>
#include <hip/hip_bf16.h>

// AdLIF SNN forward, MI355X. B=512, T=500, NIN=96, H=512, NOUT=2.
//
// One block per batch row, 512 threads (8 waves), wave wv owns h in
// [wv*64, wv*64+64). 64-step chunks, NPH=8 phases, ONE barrier per phase.
//
// - x staged in LDS bf16 with TIME-PERMUTED rows: LDS row s*16+4q+j holds
//   t_local = 16q+4s+j. After the 4 subtile MFMAs (D row = 4*lq+reg), lane
//   lq holds 16 CONSECUTIVE timesteps [16lq,16lq+16) per owned h.
// - Speculative scan entirely in registers off the f32 accumulators:
//   d = fma(al, d, c) x16 per segment (+ running max), then ONE cross-lane
//   composition per chunk: exchange segment composites via shfl_xor(16/32),
//   compose with al^16. No I' LDS round-trip at all.
// - Spike detection: max_t v_t <= max_d + |v_start| (sound since al<1).
//   If >1: flag -> rollback to 1-deep checkpoint (a,spk provably 0), exact
//   cold path (identity restage, per-16-subtile I in LDS, full Wrec
//   recurrence), sticky to end. Never taken on this data; exact if taken.
// - Partial chunk 7 (52 steps): zero-filled x; last segment gets exact
//   al^-12 correction (zero-input steps only multiply by al).

#define B_ 512
#define T_ 500
#define NIN_ 96
#define H_ 512
#define CH 64
#define NPH 8
#define LASTN 52
#define XPAD 104        // shorts per x row (208 B pitch, 16B-aligned)
#define PTC 24          // cold-path I pitch (shorts)

typedef __attribute__((ext_vector_type(8))) short bf16x8;  // 8 bf16 = 4 VGPR
typedef __attribute__((ext_vector_type(4))) float f32x4;

__device__ __forceinline__ unsigned short f2bf(float f) {
    union { __hip_bfloat16 h; unsigned short s; } u;
    u.h = __float2bfloat16(f);
    return u.s;
}
__device__ __forceinline__ unsigned pk2(float lo, float hi) {
    return (unsigned)f2bf(lo) | ((unsigned)f2bf(hi) << 16);
}

// Exact AdLIF cold path. Irow holds I' = oma*I (bf16, oma folded in).
__device__ __noinline__ void exact_steps(
    int nsteps, const unsigned short* Irow, float* spk_lds,
    const float* __restrict__ Wrec, int tid,
    float al, float oma, float rh, float be,
    float& v, float& a, float& spk)
{
    for (int tt = 0; tt < nsteps; ++tt) {
        float Ip = __uint_as_float(((unsigned)Irow[tt]) << 16);
        float racc = 0.f;
        for (int hp = 0; hp < H_; ++hp) {
            if (spk_lds[hp] != 0.f) racc += Wrec[(size_t)tid * H_ + hp];
        }
        float vnew = (al * v) * (1.f - spk) + Ip + oma * (racc - a);
        spk = (vnew - 1.f) > 0.f ? 1.f : 0.f;
        a = fmaf(be, spk, rh * a);
        v = vnew;
        __syncthreads();
        spk_lds[tid] = spk;
        __syncthreads();
    }
}

__global__ __launch_bounds__(512, 4) void snn_regscan(
    const float* __restrict__ x,      // [B, T, NIN]
    const float* __restrict__ W1,     // [H, NIN]
    const float* __restrict__ Wrec,   // [H, H]
    const float* __restrict__ W2,     // [2, H]
    const float* __restrict__ alpha,  // [H]
    const float* __restrict__ rho,    // [H]
    const float* __restrict__ beta_a, // [H]
    float* __restrict__ out)          // [B, 2]
{
    const int b    = blockIdx.x;
    const int tid  = threadIdx.x;
    const int wv   = tid >> 6;
    const int lane = tid & 63;
    const int lq   = lane >> 4;
    const int lr   = lane & 15;

    __shared__ __align__(16) unsigned short xlds[2][CH * XPAD]; // 26.6 KB
    __shared__ __align__(16) unsigned short Icold[H_ * PTC];    // 24 KB (cold)
    __shared__ float spk_lds[H_];
    __shared__ int   flagLds[4];   // chunk j -> slot j&3
    __shared__ float red[16];

    // W1 fragments (persistent, B operand), oma = 1-alpha folded in.
    bf16x8 wfrag[4][3];
    float al_[4], al16_[4];
    #pragma unroll
    for (int i = 0; i < 4; ++i) {
        const int h = wv * 64 + i * 16 + lr;
        const float av = alpha[h];
        al_[i] = av;
        float a2 = av * av, a4 = a2 * a2, a8 = a4 * a4;
        al16_[i] = a8 * a8;
        const float omaf = 1.0f - av;
        const float* wrow = W1 + h * NIN_;
        #pragma unroll
        for (int kb = 0; kb < 3; ++kb) {
            const float* p = wrow + kb * 32 + lq * 8;
            float4 u0 = *reinterpret_cast<const float4*>(p);
            float4 u1 = *reinterpret_cast<const float4*>(p + 4);
            union { unsigned d[4]; bf16x8 v8; } pk;
            pk.d[0] = pk2(omaf * u0.x, omaf * u0.y);
            pk.d[1] = pk2(omaf * u0.z, omaf * u0.w);
            pk.d[2] = pk2(omaf * u1.x, omaf * u1.y);
            pk.d[3] = pk2(omaf * u1.z, omaf * u1.w);
            wfrag[i][kb] = pk.v8;
        }
    }

    // x staging: all 512 threads; thread covers t_local = st, 12 floats.
    const float4* xb4 = reinterpret_cast<const float4*>(x + (size_t)b * T_ * NIN_);
    const int st = tid >> 3, sq = tid & 7;
    // time-permuted row: row s*16+4q+j holds t_local = 16q+4s+j
    const int rwPerm = ((st & 15) >> 2) * 16 + (st >> 4) * 4 + (st & 3);
    float4 xr0, xr1, xr2;
    auto XLOAD = [&](int c) {
        int t = c * CH + st;
        if (t < T_) {
            const float4* p = xb4 + t * 24 + sq * 3;
            xr0 = p[0]; xr1 = p[1]; xr2 = p[2];
        } else {
            xr0 = make_float4(0.f, 0.f, 0.f, 0.f);
            xr1 = xr0; xr2 = xr0;
        }
    };
    auto XWRITE = [&](int buf, int row) {
        unsigned short* base = &xlds[buf][row * XPAD + sq * 12];
        *reinterpret_cast<uint2*>(base)     = make_uint2(pk2(xr0.x, xr0.y), pk2(xr0.z, xr0.w));
        *reinterpret_cast<uint2*>(base + 4) = make_uint2(pk2(xr1.x, xr1.y), pk2(xr1.z, xr1.w));
        *reinterpret_cast<uint2*>(base + 8) = make_uint2(pk2(xr2.x, xr2.y), pk2(xr2.z, xr2.w));
    };
    auto SUBT = [&](int buf, int s, f32x4* acc) {
        const f32x4 zero = {0.f, 0.f, 0.f, 0.f};
        #pragma unroll
        for (int i = 0; i < 4; ++i) acc[i] = zero;
        #pragma unroll
        for (int kb = 0; kb < 3; ++kb) {
            bf16x8 xf = *reinterpret_cast<const bf16x8*>(
                &xlds[buf][(s * 16 + lr) * XPAD + kb * 32 + lq * 8]);
            #pragma unroll
            for (int i = 0; i < 4; ++i)
                acc[i] = __builtin_amdgcn_mfma_f32_16x16x32_bf16(
                    xf, wfrag[i][kb], acc[i], 0, 0, 0);
        }
    };

    float v_[4]  = {0.f, 0.f, 0.f, 0.f};
    float vck[4] = {0.f, 0.f, 0.f, 0.f};
    if (tid < 4) flagLds[tid] = 0;
    XLOAD(0); XWRITE(0, rwPerm);   // chunk 0 (permuted) into buf 0
    XLOAD(1);                      // chunk 1 in flight
    __syncthreads();

    int coldF = -1;

    for (int p = 0; p < NPH; ++p) {
        // speculation check for chunk p-1 (flag set before last barrier)
        if (p >= 1 && flagLds[(p - 1) & 3] != 0) { coldF = p - 1; break; }
        if (tid == 0) flagLds[(p + 1) & 3] = 0;
        #pragma unroll
        for (int i = 0; i < 4; ++i) vck[i] = v_[i];   // chunk-p checkpoint

        // MFMA + in-register fold: lane lq accumulates its 16 consecutive
        // steps (t = 16lq + 4s + j) into d_[i]; mx tracks max of the chain.
        float d_[4] = {0.f, 0.f, 0.f, 0.f};
        float mx[4] = {-3.4e38f, -3.4e38f, -3.4e38f, -3.4e38f};
        #pragma unroll
        for (int s = 0; s < 4; ++s) {
            f32x4 acc[4];
            SUBT(p & 1, s, acc);
            #pragma unroll
            for (int j = 0; j < 4; ++j)
                #pragma unroll
                for (int i = 0; i < 4; ++i) {
                    d_[i] = fmaf(al_[i], d_[i], acc[i][j]);
                    mx[i] = fmaxf(mx[i], d_[i]);
                }
        }

        if (p + 1 < NPH) XWRITE((p + 1) & 1, rwPerm);
        if (p + 2 < NPH) XLOAD(p + 2);

        // cross-lane composition: gather 4 segment composites, chain with al^16
        const bool b0 = (lq & 1) != 0, b1 = (lq & 2) != 0;
        bool trip = false;
        #pragma unroll
        for (int i = 0; i < 4; ++i) {
            float A  = d_[i];
            float Bv = __shfl_xor(A, 16);
            float Cv = __shfl_xor(A, 32);
            float Dv = __shfl_xor(Bv, 32);
            float x0 = b0 ? Bv : A;
            float x1 = b0 ? A  : Bv;
            float x2 = b0 ? Dv : Cv;
            float x3 = b0 ? Cv : Dv;
            float e0 = b1 ? x2 : x0;   // ordered D_0..D_3
            float e1 = b1 ? x3 : x1;
            float e2 = b1 ? x0 : x2;
            float e3 = b1 ? x1 : x3;
            float k16 = al16_[i];
            float w1 = fmaf(k16, v_[i], e0);
            float w2 = fmaf(k16, w1, e1);
            float w3 = fmaf(k16, w2, e2);
            float w4 = fmaf(k16, w3, e3);
            float vs = (lq == 0) ? v_[i] : (lq == 1) ? w1 : (lq == 2) ? w2 : w3;
            trip = trip || ((mx[i] + fabsf(vs)) > 1.0f);   // sound bound
            if (p == NPH - 1) {
                // last segment had 12 zero-input (decay-only) steps
                float a2 = al_[i] * al_[i], a4 = a2 * a2;
                w4 = w4 * (a4 / al16_[i]);                 // * al^-12
            }
            v_[i] = w4;
        }
        if (trip) flagLds[p & 3] = 1;   // benign race, all store 1
        __syncthreads();                // xlds[(p+1)&1] ready; flag visible
    }
    if (coldF < 0 && flagLds[(NPH - 1) & 3] != 0) coldF = NPH - 1;

    bool ex = false;
    float vex = 0.f;
    if (coldF >= 0) {
        // rollback: v at start of chunk coldF; a,spk provably 0.
        float vv = (lq == 0) ? vck[0] : (lq == 1) ? vck[1]
                 : (lq == 2) ? vck[2] : vck[3];
        float aa = 0.f, ss = 0.f;
        const float alc  = alpha[tid];
        const float omac = 1.0f - alc;
        const float rhc  = rho[tid];
        const float bec  = beta_a[tid];
        spk_lds[tid] = 0.f;
        #pragma unroll 1
        for (int jj = coldF; jj < NPH; ++jj) {
            __syncthreads();
            XLOAD(jj); XWRITE(0, st);      // IDENTITY rows into buf 0
            __syncthreads();
            int remain = (jj == NPH - 1) ? LASTN : CH;
            #pragma unroll 1
            for (int s = 0; s < 4 && remain > 0; ++s) {
                f32x4 acc[4];
                SUBT(0, s, acc);
                #pragma unroll
                for (int i = 0; i < 4; ++i) {
                    const int h = wv * 64 + i * 16 + lr;
                    *reinterpret_cast<uint2*>(&Icold[h * PTC + lq * 4]) =
                        make_uint2(pk2(acc[i][0], acc[i][1]),
                                   pk2(acc[i][2], acc[i][3]));
                }
                __syncthreads();
                int ns = remain < 16 ? remain : 16;
                exact_steps(ns, &Icold[tid * PTC], spk_lds, Wrec, tid,
                            alc, omac, rhc, bec, vv, aa, ss);
                remain -= ns;
            }
        }
        vex = vv;
        ex = true;
    }

    // Readout: out[b,n] = sum_h v_h * W2[n,h]
    float p0, p1;
    if (ex) {
        p0 = vex * W2[tid];
        p1 = vex * W2[H_ + tid];
    } else {
        p0 = 0.f; p1 = 0.f;
        if (lq == 0) {   // v replicated over lq; count each h once
            #pragma unroll
            for (int i = 0; i < 4; ++i) {
                const int h = wv * 64 + i * 16 + lr;
                p0 += v_[i] * W2[h];
                p1 += v_[i] * W2[H_ + h];
            }
        }
    }
    #pragma unroll
    for (int off = 32; off > 0; off >>= 1) {
        p0 += __shfl_down(p0, off, 64);
        p1 += __shfl_down(p1, off, 64);
    }
    if (lane == 0) { red[wv * 2] = p0; red[wv * 2 + 1] = p1; }
    __syncthreads();
    if (tid == 0) {
        float s0 = 0.f, s1 = 0.f;
        #pragma unroll
        for (int w8 = 0; w8 < 8; ++w8) { s0 += red[w8 * 2]; s1 += red[w8 * 2 + 1]; }
        out[b * 2 + 0] = s0;
        out[b * 2 + 1] = s1;
    }
}

extern "C" void kernel_launch(void* const* d_in, const int* in_sizes, int n_in,
                              void* d_out, int out_size, void* d_ws, size_t ws_size,
                              hipStream_t stream) {
    const float* x      = (const float*)d_in[0];
    const float* W1     = (const float*)d_in[1];
    const float* Wrec   = (const float*)d_in[2];
    const float* W2     = (const float*)d_in[3];
    const float* alpha  = (const float*)d_in[4];
    const float* rho    = (const float*)d_in[5];
    const float* beta_a = (const float*)d_in[6];
    float* out = (float*)d_out;

    snn_regscan<<<dim3(B_), dim3(H_), 0, stream>>>(x, W1, Wrec, W2, alpha, rho, beta_a, out);
}